// Round 1
// baseline (497.659 us; speedup 1.0000x reference)
//
#include <hip/hip_runtime.h>
#include <stdint.h>

// Problem constants
#define A_    10
#define NPA_  192
#define C_    128
#define N_    1920      // A_*NPA_
#define M_    32768     // B*T
#define OUTC  1280      // A_*C_
#define MT    16        // rows per block tile
#define RS    1928      // padded LDS row stride in bf16 elems (1920+8 -> 16B-aligned rows, stride%32dw==4 -> 2-way max on b128)

typedef __attribute__((ext_vector_type(8))) short  short8;
typedef __attribute__((ext_vector_type(4))) float  float4v;

__device__ __forceinline__ unsigned short f2bf(float f) {
  unsigned u = __builtin_bit_cast(unsigned, f);
  u += 0x7FFFu + ((u >> 16) & 1u);           // round-to-nearest-even
  return (unsigned short)(u >> 16);
}

// Block 0 / wave 0: build dest[p] = a*192 + rank(p within area a), matching np.where ascending order.
// Blocks 1..960: transpose W (A,NPA,C) fp32 -> Wt[a][c][k] bf16.
__global__ __launch_bounds__(256) void prep_kernel(const float* __restrict__ W,
                                                   const int* __restrict__ nr,
                                                   unsigned short* __restrict__ Wt,
                                                   int* __restrict__ dest) {
  if (blockIdx.x == 0) {
    int lane = threadIdx.x;
    if (lane < 64) {
      int cnt[A_];
#pragma unroll
      for (int i = 0; i < A_; ++i) cnt[i] = 0;
      unsigned long long lt = (1ull << lane) - 1ull;
      for (int ch = 0; ch < N_ / 64; ++ch) {
        int p = ch * 64 + lane;
        int a = nr[p];
        int base = 0, rank = 0;
#pragma unroll
        for (int aa = 0; aa < A_; ++aa) {
          unsigned long long m = __ballot(a == aa);
          if (a == aa) { base = cnt[aa]; rank = __popcll(m & lt); }
          cnt[aa] += __popcll(m);
        }
        dest[p] = a * NPA_ + base + rank;
      }
    }
  } else {
    int o  = (blockIdx.x - 1) * 256 + threadIdx.x;   // 0..245759 exactly
    int ac = o / NPA_;
    int k  = o - ac * NPA_;
    int a  = ac >> 7;
    int c  = ac & 127;
    Wt[o] = f2bf(W[(a * NPA_ + k) * C_ + c]);
  }
}

// Main: per block, stage 16 rows x 1920 cols of x (contiguous global range) as bf16
// scattered into permuted LDS layout xs[m][a*192+n]; then 4 waves x 20 (area,ctile)
// 16x16 output tiles, K=192 via 6x mfma_f32_16x16x32_bf16.
__global__ __launch_bounds__(256, 2) void stitch_kernel(const float* __restrict__ x,
                                                        const unsigned short* __restrict__ Wt,
                                                        const float* __restrict__ bias,
                                                        const int* __restrict__ dest,
                                                        float* __restrict__ out) {
  __shared__ unsigned short xs[MT * RS];   // 61,696 B -> 2 blocks/CU

  const int tid = threadIdx.x;
  const int mb  = blockIdx.x * MT;

  // ---- stage x tile (coalesced float4 reads, bf16 scatter writes) ----
  const float4* xp = (const float4*)(x + (size_t)mb * N_);
  const int4*   dp = (const int4*)dest;
#pragma unroll
  for (int i = 0; i < 30; ++i) {
    int g   = i * 256 + tid;          // float4 index in tile, 0..7679
    int row = g / 480;
    int c4  = g - row * 480;
    float4 v = xp[g];
    int4   d = dp[c4];
    unsigned short* base = xs + row * RS;
    base[d.x] = f2bf(v.x);
    base[d.y] = f2bf(v.y);
    base[d.z] = f2bf(v.z);
    base[d.w] = f2bf(v.w);
  }
  __syncthreads();

  const int wave = tid >> 6;
  const int lane = tid & 63;
  const int l15  = lane & 15;
  const int lq   = lane >> 4;

  short8 af[6];
  int    cur_a = -1;
  const int t0 = wave * 20;

  // prefetch B-fragments for first tile
  short8 bf[6];
  {
    int t = t0, a = t >> 3, cc = t & 7;
    const short8* wp = (const short8*)(Wt + (size_t)(a * C_ + cc * 16 + l15) * NPA_);
#pragma unroll
    for (int ks = 0; ks < 6; ++ks) bf[ks] = wp[ks * 4 + lq];
  }

  for (int t = t0; t < t0 + 20; ++t) {
    int a = t >> 3, cc = t & 7;
    if (a != cur_a) {
#pragma unroll
      for (int ks = 0; ks < 6; ++ks)
        af[ks] = *(const short8*)&xs[l15 * RS + a * NPA_ + ks * 32 + lq * 8];
      cur_a = a;
    }
    float bv = bias[a * C_ + cc * 16 + l15];

    short8 bfn[6];
    if (t + 1 < t0 + 20) {
      int t2 = t + 1, a2 = t2 >> 3, cc2 = t2 & 7;
      const short8* wp2 = (const short8*)(Wt + (size_t)(a2 * C_ + cc2 * 16 + l15) * NPA_);
#pragma unroll
      for (int ks = 0; ks < 6; ++ks) bfn[ks] = wp2[ks * 4 + lq];
    }

    float4v acc = {0.f, 0.f, 0.f, 0.f};
#pragma unroll
    for (int ks = 0; ks < 6; ++ks)
      acc = __builtin_amdgcn_mfma_f32_16x16x32_bf16(af[ks], bf[ks], acc, 0, 0, 0);

    // C/D layout: col = lane&15, row = (lane>>4)*4 + r
    float* op = out + (size_t)(mb + lq * 4) * OUTC + a * C_ + cc * 16 + l15;
#pragma unroll
    for (int r = 0; r < 4; ++r) op[(size_t)r * OUTC] = acc[r] + bv;

#pragma unroll
    for (int ks = 0; ks < 6; ++ks) bf[ks] = bfn[ks];
  }
}

extern "C" void kernel_launch(void* const* d_in, const int* in_sizes, int n_in,
                              void* d_out, int out_size, void* d_ws, size_t ws_size,
                              hipStream_t stream) {
  const float* x    = (const float*)d_in[0];   // (32,1024,1920) f32
  const float* W    = (const float*)d_in[1];   // (10,192,128)   f32
  const float* b    = (const float*)d_in[2];   // (10,128)       f32
  const int*   nr   = (const int*)  d_in[3];   // (32,1920) int32 (row 0 used)
  float*       out  = (float*)d_out;           // (32,1024,1280) f32

  unsigned short* Wt   = (unsigned short*)d_ws;                  // 491,520 B
  int*            dest = (int*)((char*)d_ws + 491520);           // 7,680 B

  prep_kernel<<<dim3(961), dim3(256), 0, stream>>>(W, nr, Wt, dest);
  stitch_kernel<<<dim3(M_ / MT), dim3(256), 0, stream>>>(x, Wt, b, dest, out);
}